// Round 2
// baseline (1090.103 us; speedup 1.0000x reference)
//
#include <hip/hip_runtime.h>
#include <cstdint>

#define N_NODES   10000
#define N_EDGES   640000
#define NODE_OUT  (N_NODES * 128)       // 1,280,000 node-output floats

typedef __bf16 bf16;
typedef bf16  bf16x8 __attribute__((ext_vector_type(8)));
typedef float f32x4  __attribute__((ext_vector_type(4)));

// transposed bf16 weight offsets inside ws ([N][K] row-major, elements)
#define EW1T_OFF 0        // 128 x 384
#define EW2T_OFF 49152    // 128 x 128
#define NW1T_OFF 65536    // 128 x 256
#define NW2T_OFF 98304    // 128 x 128

// -------- weight convert+transpose: fp32 W[K][N] -> bf16 WT[N][K] --------
__global__ void transpose_weights(const float* __restrict__ eW1, const float* __restrict__ eW2,
                                  const float* __restrict__ nW1, const float* __restrict__ nW2,
                                  bf16* __restrict__ wt) {
  int gid = blockIdx.x * 256 + threadIdx.x;   // 448*256 = 114688 exactly
  const float* src; bf16* dst; int K, off;
  if (gid < 49152)      { src = eW1; dst = wt + EW1T_OFF; K = 384; off = gid; }
  else if (gid < 65536) { src = eW2; dst = wt + EW2T_OFF; K = 128; off = gid - 49152; }
  else if (gid < 98304) { src = nW1; dst = wt + NW1T_OFF; K = 256; off = gid - 65536; }
  else                  { src = nW2; dst = wt + NW2T_OFF; K = 128; off = gid - 98304; }
  int k = off >> 7, n = off & 127;
  dst[n * K + k] = (bf16)src[off];
}

__device__ __forceinline__ float softplus_f(float v) {
  return v > 20.f ? v : __logf(1.f + __expf(v));
}

// load 8 consecutive fp32 and round to a bf16x8 fragment
__device__ __forceinline__ bf16x8 load_cvt8(const float* __restrict__ src) {
  float4 f0 = *(const float4*)src;
  float4 f1 = *(const float4*)(src + 4);
  bf16x8 h;
  h[0] = (bf16)f0.x; h[1] = (bf16)f0.y; h[2] = (bf16)f0.z; h[3] = (bf16)f0.w;
  h[4] = (bf16)f1.x; h[5] = (bf16)f1.y; h[6] = (bf16)f1.z; h[7] = (bf16)f1.w;
  return h;
}

// One GEMM over the edge tile: C[64,128] tile = A(sA slots SLOT_BASE..) x WT^T.
// sA: [64 rows][48 slots of 16B], physical slot = logical ^ (row & 7).
// B fragments are loaded straight from global (L2-resident 229KB weight table)
// in MFMA B-layout: lane(ln15,lq) of tile tn reads WT[n0+tn*16+ln15][c*32+lq*8 ..+7].
// NO LDS staging for B, NO per-chunk barriers.
template <int K, int SLOT_BASE>
__device__ __forceinline__ void run_gemm(const bf16* __restrict__ WT,
                                         const bf16* sA,
                                         int lane, int m0, int n0,
                                         f32x4 (&acc)[2][4]) {
  const int ln15 = lane & 15, lq = lane >> 4;
  constexpr int NC = K >> 5;
  const int r0 = m0 + ln15, r1 = r0 + 16;
  const int sw = ln15 & 7;                    // == r0&7 == r1&7
  #pragma unroll
  for (int tm = 0; tm < 2; ++tm)
    #pragma unroll
    for (int tn = 0; tn < 4; ++tn)
      acc[tm][tn] = f32x4{0.f, 0.f, 0.f, 0.f};

  const bf16* bbase = WT + (size_t)(n0 + ln15) * K + lq * 8;

  #pragma unroll
  for (int c = 0; c < NC; ++c) {
    const int ls = SLOT_BASE + (c << 2) + lq;
    bf16x8 a0 = *(const bf16x8*)&sA[r0 * 384 + ((ls ^ sw) << 3)];
    bf16x8 a1 = *(const bf16x8*)&sA[r1 * 384 + ((ls ^ sw) << 3)];
    #pragma unroll
    for (int tn = 0; tn < 4; ++tn) {
      bf16x8 b = *(const bf16x8*)(bbase + tn * 16 * K + (c << 5));
      acc[0][tn] = __builtin_amdgcn_mfma_f32_16x16x32_bf16(a0, b, acc[0][tn], 0, 0, 0);
      acc[1][tn] = __builtin_amdgcn_mfma_f32_16x16x32_bf16(a1, b, acc[1][tn], 0, 0, 0);
    }
  }
}

// ---------------- fused per-edge MLP ----------------
// 64-edge tile, 256 threads (4 waves), sA only = 49,152 B -> 3 blocks/CU.
__global__ void __launch_bounds__(256, 3)
fused_mpnn(const float* __restrict__ x, const int* __restrict__ eidx,
           const float* __restrict__ edge_attr,
           const float* __restrict__ eb1, const float* __restrict__ eb2,
           const float* __restrict__ nb1, const float* __restrict__ nb2,
           const bf16* __restrict__ wt,
           float* __restrict__ node_out, float* __restrict__ edge_out)
{
  extern __shared__ char smem[];
  bf16* sA = (bf16*)smem;               // [64][384] swizzled, 49,152 B

  const int tid  = threadIdx.x;
  const int wave = tid >> 6, lane = tid & 63;
  const int ln15 = lane & 15, lq = lane >> 4;
  const int m0 = (wave >> 1) * 32;      // 0,32
  const int n0 = (wave & 1) * 64;      // 0,64
  const int e0 = blockIdx.x * 64;

  // ---- stage A tile: slots 0-15 x_row | 16-31 x_col | 32-47 edge_attr ----
  #pragma unroll
  for (int it = 0; it < 12; ++it) {
    int j  = it * 256 + tid;            // 0..3071 16B-LDS-chunks
    int region = j >> 10;               // uniform per it
    int jj = j & 1023;
    int e  = jj >> 4, pl = jj & 15;     // physical slot within region
    int lp = pl ^ (e & 7);              // logical slot this thread stages
    const float* src;
    if (region == 0)      src = x + (size_t)eidx[e0 + e] * 128 + lp * 8;
    else if (region == 1) src = x + (size_t)eidx[N_EDGES + e0 + e] * 128 + lp * 8;
    else                  src = edge_attr + (size_t)(e0 + e) * 128 + lp * 8;
    *(bf16x8*)&sA[e * 384 + ((region << 4) + pl) * 8] = load_cvt8(src);
  }
  __syncthreads();                      // sA visible to all waves

  f32x4 acc[2][4];

  // ---- GEMM1: [x_row|x_col|edge_attr] @ eW1, softplus -> C1 (slots 32-47) ----
  run_gemm<384, 0>(wt + EW1T_OFF, sA, lane, m0, n0, acc);
  __syncthreads();                      // pair-wave finished reading sA rows
  {
    float bias[4];
    #pragma unroll
    for (int tn = 0; tn < 4; ++tn) bias[tn] = eb1[n0 + tn * 16 + ln15];
    #pragma unroll
    for (int tm = 0; tm < 2; ++tm)
      #pragma unroll
      for (int tn = 0; tn < 4; ++tn)
        #pragma unroll
        for (int r = 0; r < 4; ++r) {
          float v = softplus_f(acc[tm][tn][r] + bias[tn]);
          int row = m0 + tm * 16 + lq * 4 + r;
          int col = n0 + tn * 16 + ln15;
          int ls  = 32 + (col >> 3);
          sA[row * 384 + ((ls ^ (row & 7)) << 3) + (col & 7)] = (bf16)v;
        }
  }
  __syncthreads();                      // C1 visible

  // ---- GEMM2: C1 @ eW2 + eb2 -> edge_out (fp32 global) and C2 (slots 16-31) ----
  run_gemm<128, 32>(wt + EW2T_OFF, sA, lane, m0, n0, acc);
  __syncthreads();
  {
    float bias[4];
    #pragma unroll
    for (int tn = 0; tn < 4; ++tn) bias[tn] = eb2[n0 + tn * 16 + ln15];
    #pragma unroll
    for (int tm = 0; tm < 2; ++tm)
      #pragma unroll
      for (int tn = 0; tn < 4; ++tn)
        #pragma unroll
        for (int r = 0; r < 4; ++r) {
          float v = acc[tm][tn][r] + bias[tn];
          int row = m0 + tm * 16 + lq * 4 + r;
          int col = n0 + tn * 16 + ln15;
          edge_out[(size_t)(e0 + row) * 128 + col] = v;
          int ls = 16 + (col >> 3);
          sA[row * 384 + ((ls ^ (row & 7)) << 3) + (col & 7)] = (bf16)v;
        }
  }
  __syncthreads();                      // C2 visible

  // ---- GEMM3: [x_row|C2] @ nW1, softplus -> C3 (slots 32-47) ----
  run_gemm<256, 0>(wt + NW1T_OFF, sA, lane, m0, n0, acc);
  __syncthreads();
  {
    float bias[4];
    #pragma unroll
    for (int tn = 0; tn < 4; ++tn) bias[tn] = nb1[n0 + tn * 16 + ln15];
    #pragma unroll
    for (int tm = 0; tm < 2; ++tm)
      #pragma unroll
      for (int tn = 0; tn < 4; ++tn)
        #pragma unroll
        for (int r = 0; r < 4; ++r) {
          float v = softplus_f(acc[tm][tn][r] + bias[tn]);
          int row = m0 + tm * 16 + lq * 4 + r;
          int col = n0 + tn * 16 + ln15;
          int ls  = 32 + (col >> 3);
          sA[row * 384 + ((ls ^ (row & 7)) << 3) + (col & 7)] = (bf16)v;
        }
  }
  __syncthreads();                      // C3 visible

  // ---- GEMM4: C3 @ nW2 + nb2 -> fp32 atomic scatter into node_out by col ----
  run_gemm<128, 32>(wt + NW2T_OFF, sA, lane, m0, n0, acc);
  {
    float bias[4];
    #pragma unroll
    for (int tn = 0; tn < 4; ++tn) bias[tn] = nb2[n0 + tn * 16 + ln15];
    #pragma unroll
    for (int tm = 0; tm < 2; ++tm) {
      int nodes[4];
      #pragma unroll
      for (int r = 0; r < 4; ++r)
        nodes[r] = eidx[N_EDGES + e0 + m0 + tm * 16 + lq * 4 + r];
      #pragma unroll
      for (int tn = 0; tn < 4; ++tn) {
        int col = n0 + tn * 16 + ln15;
        #pragma unroll
        for (int r = 0; r < 4; ++r) {
          float v = acc[tm][tn][r] + bias[tn];
          unsafeAtomicAdd(&node_out[(size_t)nodes[r] * 128 + col], v);
        }
      }
    }
  }
}

extern "C" void kernel_launch(void* const* d_in, const int* in_sizes, int n_in,
                              void* d_out, int out_size, void* d_ws, size_t ws_size,
                              hipStream_t stream) {
  const float* x    = (const float*)d_in[0];
  const int*   eidx = (const int*)d_in[1];
  const float* ea   = (const float*)d_in[2];
  const float* nW1  = (const float*)d_in[3];
  const float* nb1  = (const float*)d_in[4];
  const float* nW2  = (const float*)d_in[5];
  const float* nb2  = (const float*)d_in[6];
  const float* eW1  = (const float*)d_in[7];
  const float* eb1  = (const float*)d_in[8];
  const float* eW2  = (const float*)d_in[9];
  const float* eb2  = (const float*)d_in[10];

  bf16*  wt        = (bf16*)d_ws;                 // 114,688 bf16 = 229,376 B
  float* out_nodes = (float*)d_out;               // [10000,128]
  float* out_edges = out_nodes + NODE_OUT;        // [640000,128]

  hipMemsetAsync(out_nodes, 0, NODE_OUT * sizeof(float), stream);
  transpose_weights<<<448, 256, 0, stream>>>(eW1, eW2, nW1, nW2, wt);
  fused_mpnn<<<N_EDGES / 64, 256, 49152, stream>>>(
      x, eidx, ea, eb1, eb2, nb1, nb2, wt, out_nodes, out_edges);
}

// Round 3
// 992.549 us; speedup vs baseline: 1.0983x; 1.0983x over previous
//
#include <hip/hip_runtime.h>
#include <cstdint>

#define N_NODES   10000
#define N_EDGES   640000
#define NODE_OUT  (N_NODES * 128)       // 1,280,000 node-output floats

typedef __bf16 bf16;
typedef bf16  bf16x8 __attribute__((ext_vector_type(8)));
typedef float f32x4  __attribute__((ext_vector_type(4)));

// transposed bf16 weight offsets inside ws ([N][K] row-major, elements)
#define EW1T_OFF 0        // 128 x 384
#define EW2T_OFF 49152    // 128 x 128
#define NW1T_OFF 65536    // 128 x 256
#define NW2T_OFF 98304    // 128 x 128

// -------- weight convert+transpose: fp32 W[K][N] -> bf16 WT[N][K] --------
__global__ void transpose_weights(const float* __restrict__ eW1, const float* __restrict__ eW2,
                                  const float* __restrict__ nW1, const float* __restrict__ nW2,
                                  bf16* __restrict__ wt) {
  int gid = blockIdx.x * 256 + threadIdx.x;   // 448*256 = 114688 exactly
  const float* src; bf16* dst; int K, off;
  if (gid < 49152)      { src = eW1; dst = wt + EW1T_OFF; K = 384; off = gid; }
  else if (gid < 65536) { src = eW2; dst = wt + EW2T_OFF; K = 128; off = gid - 49152; }
  else if (gid < 98304) { src = nW1; dst = wt + NW1T_OFF; K = 256; off = gid - 65536; }
  else                  { src = nW2; dst = wt + NW2T_OFF; K = 128; off = gid - 98304; }
  int k = off >> 7, n = off & 127;
  dst[n * K + k] = (bf16)src[off];
}

__device__ __forceinline__ float softplus_f(float v) {
  return v > 20.f ? v : __logf(1.f + __expf(v));
}

// load 8 consecutive fp32 and round to a bf16x8 fragment
__device__ __forceinline__ bf16x8 load_cvt8(const float* __restrict__ src) {
  float4 f0 = *(const float4*)src;
  float4 f1 = *(const float4*)(src + 4);
  bf16x8 h;
  h[0] = (bf16)f0.x; h[1] = (bf16)f0.y; h[2] = (bf16)f0.z; h[3] = (bf16)f0.w;
  h[4] = (bf16)f1.x; h[5] = (bf16)f1.y; h[6] = (bf16)f1.z; h[7] = (bf16)f1.w;
  return h;
}

// ================= edge MLP: GEMM1(K=384)+softplus, GEMM2(K=128) =================
// 4 waves; wave owns N-strip of 32 (n0 = wave*32), full M=64 edge tile.
// Weights register-resident: w1[12][2], w2[4][2] bf16x8 (128 VGPRs).
// sA [64][48 slots] swizzled inputs; sC [64][16 slots] swizzled C1.
// 2 barriers per tile (hazards separated cross-iteration by the same barriers).
__global__ void __launch_bounds__(256, 2)
edge_mlp(const float* __restrict__ x, const int* __restrict__ eidx,
         const float* __restrict__ edge_attr,
         const float* __restrict__ eb1, const float* __restrict__ eb2,
         const bf16* __restrict__ wt,
         float* __restrict__ edge_out)
{
  __shared__ bf16 sA[64 * 384];   // 49,152 B : slots 0-15 x_row | 16-31 x_col | 32-47 ea
  __shared__ bf16 sC[64 * 128];   // 16,384 B : C1 (softplus output), swizzled

  const int tid  = threadIdx.x;
  const int wave = tid >> 6, lane = tid & 63;
  const int ln15 = lane & 15, lq = lane >> 4;
  const int n0 = wave * 32;
  const int sw = ln15 & 7;

  // ---- register-resident weight panels ----
  bf16x8 w1[12][2], w2[4][2];
  #pragma unroll
  for (int c = 0; c < 12; ++c)
    #pragma unroll
    for (int t = 0; t < 2; ++t)
      w1[c][t] = *(const bf16x8*)&wt[EW1T_OFF + (n0 + t * 16 + ln15) * 384 + c * 32 + lq * 8];
  #pragma unroll
  for (int c = 0; c < 4; ++c)
    #pragma unroll
    for (int t = 0; t < 2; ++t)
      w2[c][t] = *(const bf16x8*)&wt[EW2T_OFF + (n0 + t * 16 + ln15) * 128 + c * 32 + lq * 8];
  float b1[2], b2[2];
  #pragma unroll
  for (int t = 0; t < 2; ++t) {
    b1[t] = eb1[n0 + t * 16 + ln15];
    b2[t] = eb2[n0 + t * 16 + ln15];
  }

  for (int tile = blockIdx.x; tile < N_EDGES / 64; tile += gridDim.x) {
    const int e0 = tile * 64;

    // ---- stage sA: 64 edges x 48 slots = 3072 chunks / 256 thr ----
    #pragma unroll
    for (int it = 0; it < 12; ++it) {
      int j  = it * 256 + tid;
      int region = j >> 10;             // uniform per it
      int jj = j & 1023;
      int e  = jj >> 4, pl = jj & 15;
      int lp = pl ^ (e & 7);
      const float* src;
      if (region == 0)      src = x + (size_t)eidx[e0 + e] * 128 + lp * 8;
      else if (region == 1) src = x + (size_t)eidx[N_EDGES + e0 + e] * 128 + lp * 8;
      else                  src = edge_attr + (size_t)(e0 + e) * 128 + lp * 8;
      *(bf16x8*)&sA[e * 384 + ((region << 4) + pl) * 8] = load_cvt8(src);
    }
    __syncthreads();   // S1: sA visible; also fences prev-iter G2 reads of sC vs this wC1

    // ---- GEMM1: sA @ w1 ----
    f32x4 acc[4][2];
    #pragma unroll
    for (int mf = 0; mf < 4; ++mf)
      #pragma unroll
      for (int t = 0; t < 2; ++t)
        acc[mf][t] = f32x4{0.f, 0.f, 0.f, 0.f};
    #pragma unroll
    for (int c = 0; c < 12; ++c) {
      bf16x8 a[4];
      #pragma unroll
      for (int mf = 0; mf < 4; ++mf)
        a[mf] = *(const bf16x8*)&sA[(mf * 16 + ln15) * 384 + ((((c << 2) + lq) ^ sw) << 3)];
      #pragma unroll
      for (int mf = 0; mf < 4; ++mf)
        #pragma unroll
        for (int t = 0; t < 2; ++t)
          acc[mf][t] = __builtin_amdgcn_mfma_f32_16x16x32_bf16(a[mf], w1[c][t], acc[mf][t], 0, 0, 0);
    }

    // ---- C1 = softplus(acc + b1) -> sC ----
    #pragma unroll
    for (int mf = 0; mf < 4; ++mf)
      #pragma unroll
      for (int t = 0; t < 2; ++t)
        #pragma unroll
        for (int r = 0; r < 4; ++r) {
          float v = softplus_f(acc[mf][t][r] + b1[t]);
          int row = mf * 16 + lq * 4 + r;
          int col = n0 + t * 16 + ln15;
          int ls  = col >> 3;
          sC[row * 128 + ((ls ^ (row & 7)) << 3) + (col & 7)] = (bf16)v;
        }
    __syncthreads();   // S2: C1 visible; also fences this-iter G1 reads vs next-iter staging

    // ---- GEMM2: sC @ w2 -> edge_out ----
    #pragma unroll
    for (int mf = 0; mf < 4; ++mf)
      #pragma unroll
      for (int t = 0; t < 2; ++t)
        acc[mf][t] = f32x4{0.f, 0.f, 0.f, 0.f};
    #pragma unroll
    for (int c = 0; c < 4; ++c) {
      bf16x8 a[4];
      #pragma unroll
      for (int mf = 0; mf < 4; ++mf)
        a[mf] = *(const bf16x8*)&sC[(mf * 16 + ln15) * 128 + ((((c << 2) + lq) ^ sw) << 3)];
      #pragma unroll
      for (int mf = 0; mf < 4; ++mf)
        #pragma unroll
        for (int t = 0; t < 2; ++t)
          acc[mf][t] = __builtin_amdgcn_mfma_f32_16x16x32_bf16(a[mf], w2[c][t], acc[mf][t], 0, 0, 0);
    }
    #pragma unroll
    for (int mf = 0; mf < 4; ++mf)
      #pragma unroll
      for (int t = 0; t < 2; ++t)
        #pragma unroll
        for (int r = 0; r < 4; ++r) {
          int row = mf * 16 + lq * 4 + r;
          int col = n0 + t * 16 + ln15;
          edge_out[(size_t)(e0 + row) * 128 + col] = acc[mf][t][r] + b2[t];
        }
  }
}

// ================= node MLP: GEMM3(K=256)+softplus, GEMM4(K=128)+scatter =================
// Same structure; inputs = [x_row | edge_out]; weights w3[8][2], w4[4][2] (96 VGPRs).
__global__ void __launch_bounds__(256, 2)
node_mlp(const float* __restrict__ x, const int* __restrict__ eidx,
         const float* __restrict__ edge_new,
         const float* __restrict__ nb1, const float* __restrict__ nb2,
         const bf16* __restrict__ wt,
         float* __restrict__ node_out)
{
  __shared__ bf16 sA[64 * 384];   // slots 0-15 x_row | 16-31 C2 | 32-47 C3

  const int tid  = threadIdx.x;
  const int wave = tid >> 6, lane = tid & 63;
  const int ln15 = lane & 15, lq = lane >> 4;
  const int n0 = wave * 32;
  const int sw = ln15 & 7;

  bf16x8 w3[8][2], w4[4][2];
  #pragma unroll
  for (int c = 0; c < 8; ++c)
    #pragma unroll
    for (int t = 0; t < 2; ++t)
      w3[c][t] = *(const bf16x8*)&wt[NW1T_OFF + (n0 + t * 16 + ln15) * 256 + c * 32 + lq * 8];
  #pragma unroll
  for (int c = 0; c < 4; ++c)
    #pragma unroll
    for (int t = 0; t < 2; ++t)
      w4[c][t] = *(const bf16x8*)&wt[NW2T_OFF + (n0 + t * 16 + ln15) * 128 + c * 32 + lq * 8];
  float b3[2], b4[2];
  #pragma unroll
  for (int t = 0; t < 2; ++t) {
    b3[t] = nb1[n0 + t * 16 + ln15];
    b4[t] = nb2[n0 + t * 16 + ln15];
  }

  for (int tile = blockIdx.x; tile < N_EDGES / 64; tile += gridDim.x) {
    const int e0 = tile * 64;

    // ---- stage slots 0-31: x_row gather | C2 (= edge_new fp32) ----
    #pragma unroll
    for (int it = 0; it < 8; ++it) {
      int j  = it * 256 + tid;
      int region = j >> 10;
      int jj = j & 1023;
      int e  = jj >> 4, pl = jj & 15;
      int lp = pl ^ (e & 7);
      const float* src = (region == 0)
          ? x + (size_t)eidx[e0 + e] * 128 + lp * 8
          : edge_new + (size_t)(e0 + e) * 128 + lp * 8;
      *(bf16x8*)&sA[e * 384 + ((region << 4) + pl) * 8] = load_cvt8(src);
    }
    __syncthreads();   // S1: staging visible; fences prev G4 reads (slots 32-47) vs this wC3

    // ---- GEMM3: sA[0..31] @ w3 ----
    f32x4 acc[4][2];
    #pragma unroll
    for (int mf = 0; mf < 4; ++mf)
      #pragma unroll
      for (int t = 0; t < 2; ++t)
        acc[mf][t] = f32x4{0.f, 0.f, 0.f, 0.f};
    #pragma unroll
    for (int c = 0; c < 8; ++c) {
      bf16x8 a[4];
      #pragma unroll
      for (int mf = 0; mf < 4; ++mf)
        a[mf] = *(const bf16x8*)&sA[(mf * 16 + ln15) * 384 + ((((c << 2) + lq) ^ sw) << 3)];
      #pragma unroll
      for (int mf = 0; mf < 4; ++mf)
        #pragma unroll
        for (int t = 0; t < 2; ++t)
          acc[mf][t] = __builtin_amdgcn_mfma_f32_16x16x32_bf16(a[mf], w3[c][t], acc[mf][t], 0, 0, 0);
    }

    // ---- C3 = softplus(acc + b3) -> slots 32-47 (disjoint from G3 reads) ----
    #pragma unroll
    for (int mf = 0; mf < 4; ++mf)
      #pragma unroll
      for (int t = 0; t < 2; ++t)
        #pragma unroll
        for (int r = 0; r < 4; ++r) {
          float v = softplus_f(acc[mf][t][r] + b3[t]);
          int row = mf * 16 + lq * 4 + r;
          int col = n0 + t * 16 + ln15;
          int ls  = 32 + (col >> 3);
          sA[row * 384 + ((ls ^ (row & 7)) << 3) + (col & 7)] = (bf16)v;
        }
    __syncthreads();   // S2: C3 visible; fences this G3 reads vs next staging

    // ---- GEMM4: sA[32..47] @ w4 -> atomic scatter ----
    #pragma unroll
    for (int mf = 0; mf < 4; ++mf)
      #pragma unroll
      for (int t = 0; t < 2; ++t)
        acc[mf][t] = f32x4{0.f, 0.f, 0.f, 0.f};
    #pragma unroll
    for (int c = 0; c < 4; ++c) {
      bf16x8 a[4];
      #pragma unroll
      for (int mf = 0; mf < 4; ++mf)
        a[mf] = *(const bf16x8*)&sA[(mf * 16 + ln15) * 384 + (((32 + (c << 2) + lq) ^ sw) << 3)];
      #pragma unroll
      for (int mf = 0; mf < 4; ++mf)
        #pragma unroll
        for (int t = 0; t < 2; ++t)
          acc[mf][t] = __builtin_amdgcn_mfma_f32_16x16x32_bf16(a[mf], w4[c][t], acc[mf][t], 0, 0, 0);
    }
    #pragma unroll
    for (int mf = 0; mf < 4; ++mf) {
      int nodes[4];
      #pragma unroll
      for (int r = 0; r < 4; ++r)
        nodes[r] = eidx[N_EDGES + e0 + mf * 16 + lq * 4 + r];
      #pragma unroll
      for (int t = 0; t < 2; ++t) {
        int col = n0 + t * 16 + ln15;
        #pragma unroll
        for (int r = 0; r < 4; ++r) {
          float v = acc[mf][t][r] + b4[t];
          unsafeAtomicAdd(&node_out[(size_t)nodes[r] * 128 + col], v);
        }
      }
    }
  }
}

extern "C" void kernel_launch(void* const* d_in, const int* in_sizes, int n_in,
                              void* d_out, int out_size, void* d_ws, size_t ws_size,
                              hipStream_t stream) {
  const float* x    = (const float*)d_in[0];
  const int*   eidx = (const int*)d_in[1];
  const float* ea   = (const float*)d_in[2];
  const float* nW1  = (const float*)d_in[3];
  const float* nb1  = (const float*)d_in[4];
  const float* nW2  = (const float*)d_in[5];
  const float* nb2  = (const float*)d_in[6];
  const float* eW1  = (const float*)d_in[7];
  const float* eb1  = (const float*)d_in[8];
  const float* eW2  = (const float*)d_in[9];
  const float* eb2  = (const float*)d_in[10];

  bf16*  wt        = (bf16*)d_ws;                 // 114,688 bf16 = 229,376 B
  float* out_nodes = (float*)d_out;               // [10000,128]
  float* out_edges = out_nodes + NODE_OUT;        // [640000,128]

  hipMemsetAsync(out_nodes, 0, NODE_OUT * sizeof(float), stream);
  transpose_weights<<<448, 256, 0, stream>>>(eW1, eW2, nW1, nW2, wt);
  edge_mlp<<<512, 256, 0, stream>>>(x, eidx, ea, eb1, eb2, wt, out_edges);
  node_mlp<<<512, 256, 0, stream>>>(x, eidx, out_edges, nb1, nb2, wt, out_nodes);
}